// Round 1
// baseline (2053.406 us; speedup 1.0000x reference)
//
#include <hip/hip_runtime.h>
#include <hip/hip_bf16.h>
#include <hip/hip_cooperative_groups.h>

namespace cg = cooperative_groups;

typedef __attribute__((ext_vector_type(4))) float f32x4;
typedef __attribute__((ext_vector_type(8))) short s16x8;

// problem constants (fixed instance)
#define NB    32
#define NDPB  32
#define SEQ   64
#define EMB   256
#define HID   512
#define NROW  1024          // NB*NDPB sentences
#define KTOT  768           // HID + EMB
#define BK    32
#define NKC   24            // KTOT/BK
#define ASTR  40            // BK+8 shorts (pad: 80B rows -> ~2-way LDS conflicts)
#define WSTR  776           // KTOT+8 shorts (1552B rows -> ~2-way)
#define ROWS_G 256          // rows per (dir,rg) group
#define NTHR  512
#define NGRID 256
#define LDSW (64 * WSTR)                  // 49664 shorts
#define LDSA (2 * ROWS_G * ASTR)          // 20480 shorts
#define LDS_BYTES ((LDSW + LDSA) * 2)     // 140288 B

// workspace layout (bytes)
#define XB_OFF   0ull                                   // bf16 x: [65536][256]
#define WHH_OFF  (XB_OFF + 65536ull * EMB * 2)          // bf16 [2][2048][512]
#define WIH_OFF  (WHH_OFF + 2ull * 2048 * HID * 2)      // bf16 [2][2048][256]
#define HB_OFF   (WIH_OFF + 2ull * 2048 * EMB * 2)      // bf16 [2 parity][2 dir][1024][512]
#define SL_OFF   (HB_OFF + 4ull * NROW * HID * 2)       // int [1024]
#define BAR_OFF  (SL_OFF + 4096ull)                     // unsigned [8]

__device__ __forceinline__ unsigned short f2bf(float f) {
    union { float f; unsigned u; } x; x.f = f;
    unsigned r = x.u + 0x7fffu + ((x.u >> 16) & 1u);   // RNE
    return (unsigned short)(r >> 16);
}
__device__ __forceinline__ void cvt8(unsigned short* dst, const float* src) {
    f32x4 v0 = *(const f32x4*)src;
    f32x4 v1 = *(const f32x4*)(src + 4);
    s16x8 o;
    o[0] = (short)f2bf(v0[0]); o[1] = (short)f2bf(v0[1]);
    o[2] = (short)f2bf(v0[2]); o[3] = (short)f2bf(v0[3]);
    o[4] = (short)f2bf(v1[0]); o[5] = (short)f2bf(v1[1]);
    o[6] = (short)f2bf(v1[2]); o[7] = (short)f2bf(v1[3]);
    *(s16x8*)dst = o;
}
__device__ __forceinline__ float sigf(float x)  { return 1.0f / (1.0f + __expf(-x)); }
__device__ __forceinline__ float tanh_(float x) { return 2.0f / (1.0f + __expf(-2.0f * x)) - 1.0f; }

__global__ void __launch_bounds__(NTHR, 2)
lstm_enc(const int* __restrict__ docs, const int* __restrict__ doc_lens,
         const float* __restrict__ embed,
         const float* __restrict__ w_ih_f, const float* __restrict__ w_hh_f, const float* __restrict__ b_f,
         const float* __restrict__ w_ih_b, const float* __restrict__ w_hh_b, const float* __restrict__ b_b,
         float* __restrict__ out, unsigned char* __restrict__ ws)
{
    extern __shared__ unsigned short lds[];
    unsigned short* Wl = lds;               // [64][WSTR]: K 0..511 = w_hh, 512..767 = w_ih
    unsigned short* Al = lds + LDSW;        // [2][ROWS_G][ASTR]

    unsigned short* xb  = (unsigned short*)(ws + XB_OFF);
    unsigned short* whh = (unsigned short*)(ws + WHH_OFF);
    unsigned short* wih = (unsigned short*)(ws + WIH_OFF);
    unsigned short* hb  = (unsigned short*)(ws + HB_OFF);
    int*       sl  = (int*)(ws + SL_OFF);
    unsigned*  bar = (unsigned*)(ws + BAR_OFF);

    const int tid = threadIdx.x;
    const int bid = blockIdx.x;
    const int gid = bid * NTHR + tid;

    // ---------------- phase 0: convert / gather / init ----------------
    // x = bf16(embed[docs]) : 65536*256 elems = 2,097,152 slots of 8
    for (int i = 0; i < 16; ++i) {
        int slot = gid + i * (NGRID * NTHR);
        int row = slot >> 5;                // sentence*64 + t
        int e   = (slot & 31) << 3;
        int tok = docs[row];
        cvt8(xb + (size_t)slot * 8, embed + (size_t)tok * EMB + e);
    }
    // w_hh (dir-major), 131072 slots per dir
    cvt8(whh + (size_t)gid * 8,             w_hh_f + (size_t)gid * 8);
    cvt8(whh + (size_t)(gid + 131072) * 8,  w_hh_b + (size_t)gid * 8);
    // w_ih, 65536 slots per dir
    {
        int dir0 = gid >> 16;
        int idx  = gid & 65535;
        cvt8(wih + (size_t)gid * 8, (dir0 ? w_ih_b : w_ih_f) + (size_t)idx * 8);
    }
    // zero parity-0 h (both dirs): 1,048,576 shorts = 131072 slots
    {
        s16x8 z = {0,0,0,0,0,0,0,0};
        *(s16x8*)(hb + (size_t)gid * 8) = z;
    }
    // sentence lengths
    if (gid < NROW) {
        int c = 0;
        const int* dr = docs + gid * SEQ;
        for (int s2 = 0; s2 < SEQ; ++s2) c += (dr[s2] != 0);
        sl[gid] = c;
    }
    if (gid < 8) bar[gid] = 0u;

    cg::this_grid().sync();

    // ---------------- decode block role ----------------
    const int grp = bid & 7;         // barrier group: 32 WGs each (same dir,rg)
    const int dir = grp >> 2;        // 0 fwd, 1 bwd
    const int rg  = grp & 3;         // row group (256 rows)
    const int cgd = bid >> 3;        // 0..31 : hidden-unit chunk of 16
    const int rowbase = rg * ROWS_G;
    const int hubase  = cgd * 16;

    // ---------------- load weight tiles into LDS ----------------
    {
        const unsigned short* whh_d = whh + (size_t)dir * 2048 * HID;
        const unsigned short* wih_d = wih + (size_t)dir * 2048 * EMB;
        for (int s2 = 0; s2 < 12; ++s2) {
            int slot = s2 * NTHR + tid;     // 0..6143 : 64 rows * 96 oct-slots
            int n  = slot / 96;
            int kq = slot - n * 96;
            int k  = kq * 8;
            int gate = n >> 4, j = n & 15;
            int gn = gate * HID + hubase + j;
            const unsigned short* src = (k < HID)
                ? (whh_d + (size_t)gn * HID + k)
                : (wih_d + (size_t)gn * EMB + (k - HID));
            *(s16x8*)(Wl + (size_t)n * WSTR + k) = *(const s16x8*)src;
        }
    }
    __syncthreads();

    // ---------------- per-lane setup ----------------
    const int wid = tid >> 6, lane = tid & 63, l15 = lane & 15, lq = lane >> 4;
    const int hu = hubase + l15;
    const float* bsrc = dir ? b_b : b_f;
    const float bi_ = bsrc[hu], bf_ = bsrc[HID + hu], bg_ = bsrc[2 * HID + hu], bo_ = bsrc[3 * HID + hu];

    int gr8[8]; int sl8[8]; float c8[8], pool8[8];
    #pragma unroll
    for (int rf = 0; rf < 2; ++rf)
        #pragma unroll
        for (int r = 0; r < 4; ++r) {
            int k8 = rf * 4 + r;
            gr8[k8] = rowbase + wid * 32 + rf * 16 + lq * 4 + r;
            sl8[k8] = sl[gr8[k8]];
            c8[k8] = 0.f; pool8[k8] = 0.f;
        }

    // ---------------- recurrence ----------------
    for (int t = 0; t < SEQ; ++t) {
        const int te = dir ? (SEQ - 1 - t) : t;
        const unsigned short* hrd = hb + (size_t)((t & 1) * 2 + dir) * NROW * HID;
        unsigned short* hwr       = hb + (size_t)((((t + 1) & 1)) * 2 + dir) * NROW * HID;

        f32x4 acc[2][4];
        #pragma unroll
        for (int rf = 0; rf < 2; ++rf)
            #pragma unroll
            for (int g = 0; g < 4; ++g)
                acc[rf][g] = (f32x4){0.f, 0.f, 0.f, 0.f};

        auto stage = [&](int kc, int buf) {
            int kbase = kc * BK;
            const unsigned short* s0; int rstr;
            if (kbase < HID) { s0 = hrd + (size_t)rowbase * HID + kbase; rstr = HID; }
            else             { s0 = xb + ((size_t)rowbase * SEQ + te) * EMB + (kbase - HID); rstr = SEQ * EMB; }
            #pragma unroll
            for (int it = 0; it < 2; ++it) {
                int slot = it * NTHR + tid;
                int row = slot >> 2, kq = slot & 3;
                *(s16x8*)(Al + ((size_t)buf * ROWS_G + row) * ASTR + kq * 8) =
                    *(const s16x8*)(s0 + (size_t)row * rstr + kq * 8);
            }
        };

        stage(0, 0);
        __syncthreads();
        for (int kc = 0; kc < NKC; ++kc) {
            int cb = kc & 1;
            if (kc + 1 < NKC) stage(kc + 1, cb ^ 1);
            const unsigned short* Ab = Al + (size_t)cb * ROWS_G * ASTR;
            s16x8 bfr[4];
            #pragma unroll
            for (int g = 0; g < 4; ++g)
                bfr[g] = *(const s16x8*)(Wl + (size_t)(g * 16 + l15) * WSTR + kc * BK + lq * 8);
            #pragma unroll
            for (int rf = 0; rf < 2; ++rf) {
                s16x8 av = *(const s16x8*)(Ab + (size_t)(wid * 32 + rf * 16 + l15) * ASTR + lq * 8);
                #pragma unroll
                for (int g = 0; g < 4; ++g)
                    acc[rf][g] = __builtin_amdgcn_mfma_f32_16x16x32_bf16(av, bfr[g], acc[rf][g], 0, 0, 0);
            }
            __syncthreads();
        }

        // elementwise LSTM update; gates g=0..3 = i,f,g,o live in same lane
        #pragma unroll
        for (int rf = 0; rf < 2; ++rf) {
            #pragma unroll
            for (int r = 0; r < 4; ++r) {
                int k8 = rf * 4 + r;
                float iv = acc[rf][0][r] + bi_;
                float fv = acc[rf][1][r] + bf_;
                float gv = acc[rf][2][r] + bg_;
                float ov = acc[rf][3][r] + bo_;
                float cc = sigf(fv) * c8[k8] + sigf(iv) * tanh_(gv);
                c8[k8] = cc;
                float hh = sigf(ov) * tanh_(cc);
                hwr[(size_t)gr8[k8] * HID + hu] = f2bf(hh);
                if (te < sl8[k8]) pool8[k8] += hh;
            }
        }

        // 32-WG group barrier (release h_t, acquire peers' h_t)
        __syncthreads();
        if (tid == 0) {
            __threadfence();
            __hip_atomic_fetch_add(bar + grp, 1u, __ATOMIC_RELAXED, __HIP_MEMORY_SCOPE_AGENT);
            unsigned tgt = 32u * (unsigned)(t + 1);
            while (__hip_atomic_load(bar + grp, __ATOMIC_RELAXED, __HIP_MEMORY_SCOPE_AGENT) < tgt)
                __builtin_amdgcn_s_sleep(1);
            __threadfence();
        }
        __syncthreads();
    }

    // ---------------- pooled output ----------------
    #pragma unroll
    for (int k8 = 0; k8 < 8; ++k8) {
        int gr = gr8[k8];
        int b = gr >> 5, d = gr & 31;
        float denom = (float)(sl8[k8] > 0 ? sl8[k8] : 1);
        float v = (d < doc_lens[b]) ? (pool8[k8] / denom) : 0.f;
        out[(size_t)gr * 1024 + (size_t)dir * HID + hu] = v;
    }
}

extern "C" void kernel_launch(void* const* d_in, const int* in_sizes, int n_in,
                              void* d_out, int out_size, void* d_ws, size_t ws_size,
                              hipStream_t stream) {
    const int*   docs     = (const int*)d_in[0];
    const int*   doc_lens = (const int*)d_in[1];
    /* d_in[2] = max_doc_len scalar (unused; fixed 32) */
    const float* embed    = (const float*)d_in[3];
    const float* w_ih_f   = (const float*)d_in[4];
    const float* w_hh_f   = (const float*)d_in[5];
    const float* b_f      = (const float*)d_in[6];
    const float* w_ih_b   = (const float*)d_in[7];
    const float* w_hh_b   = (const float*)d_in[8];
    const float* b_b      = (const float*)d_in[9];
    float* out = (float*)d_out;
    unsigned char* wsp = (unsigned char*)d_ws;

    (void)in_sizes; (void)n_in; (void)out_size; (void)ws_size;

    hipFuncSetAttribute((const void*)lstm_enc,
                        hipFuncAttributeMaxDynamicSharedMemorySize, LDS_BYTES);

    void* args[] = { &docs, &doc_lens, &embed, &w_ih_f, &w_hh_f, &b_f,
                     &w_ih_b, &w_hh_b, &b_b, &out, &wsp };
    hipLaunchCooperativeKernel((void*)lstm_enc, dim3(NGRID), dim3(NTHR),
                               args, (unsigned)LDS_BYTES, stream);
}

// Round 4
// 1943.584 us; speedup vs baseline: 1.0565x; 1.0565x over previous
//
#include <hip/hip_runtime.h>
#include <hip/hip_bf16.h>
#include <hip/hip_cooperative_groups.h>

namespace cg = cooperative_groups;

typedef __attribute__((ext_vector_type(4))) float f32x4;
typedef __attribute__((ext_vector_type(8))) short s16x8;

// problem constants (fixed instance)
#define SEQ   64
#define EMB   256
#define HID   512
#define NROW  1024          // sentences
#define NTHR  512
#define NGRID 256
#define LDS_BYTES 98304     // 24 kc * 4 gates * 64 lanes * 16B, fragment-order W

// workspace layout (bytes) — identical to the R1 (passing) layout
#define XB_OFF   0ull                                   // bf16 x: [65536][256]
#define WHH_OFF  (XB_OFF + 65536ull * EMB * 2)          // bf16 [2][2048][512]
#define WIH_OFF  (WHH_OFF + 2ull * 2048 * HID * 2)      // bf16 [2][2048][256]
#define HB_OFF   (WIH_OFF + 2ull * 2048 * EMB * 2)      // bf16 [2 parity][2 dir][1024][512]
#define SL_OFF   (HB_OFF + 4ull * NROW * HID * 2)       // int [1024]
#define BAR_OFF  (SL_OFF + 4096ull)                     // unsigned [8]

__device__ __forceinline__ unsigned short f2bf(float f) {
    union { float f; unsigned u; } x; x.f = f;
    unsigned r = x.u + 0x7fffu + ((x.u >> 16) & 1u);   // RNE
    return (unsigned short)(r >> 16);
}
__device__ __forceinline__ void cvt8(unsigned short* dst, const float* src) {
    f32x4 v0 = *(const f32x4*)src;
    f32x4 v1 = *(const f32x4*)(src + 4);
    s16x8 o;
    o[0] = (short)f2bf(v0[0]); o[1] = (short)f2bf(v0[1]);
    o[2] = (short)f2bf(v0[2]); o[3] = (short)f2bf(v0[3]);
    o[4] = (short)f2bf(v1[0]); o[5] = (short)f2bf(v1[1]);
    o[6] = (short)f2bf(v1[2]); o[7] = (short)f2bf(v1[3]);
    *(s16x8*)dst = o;
}
__device__ __forceinline__ float sigf(float x)  { return 1.0f / (1.0f + __expf(-x)); }
__device__ __forceinline__ float tanh_(float x) { return 2.0f / (1.0f + __expf(-2.0f * x)) - 1.0f; }

__global__ void __launch_bounds__(NTHR, 2)
lstm_enc(const int* __restrict__ docs, const int* __restrict__ doc_lens,
         const float* __restrict__ embed,
         const float* __restrict__ w_ih_f, const float* __restrict__ w_hh_f, const float* __restrict__ b_f,
         const float* __restrict__ w_ih_b, const float* __restrict__ w_hh_b, const float* __restrict__ b_b,
         float* __restrict__ out, unsigned char* __restrict__ ws)
{
    extern __shared__ unsigned short Wf[];   // [24 kc][4 g][64 lane][8] bf16, MFMA B-frag order

    unsigned short* xb  = (unsigned short*)(ws + XB_OFF);
    unsigned short* whh = (unsigned short*)(ws + WHH_OFF);
    unsigned short* wih = (unsigned short*)(ws + WIH_OFF);
    unsigned short* hb  = (unsigned short*)(ws + HB_OFF);
    int*       sl  = (int*)(ws + SL_OFF);
    unsigned*  bar = (unsigned*)(ws + BAR_OFF);

    const int tid = threadIdx.x;
    const int bid = blockIdx.x;
    const int gid = bid * NTHR + tid;        // 0..131071

    // ---------------- phase 0: convert / gather / init (verbatim R1) ----------------
    for (int i = 0; i < 16; ++i) {
        int slot = gid + i * (NGRID * NTHR);
        int row = slot >> 5;                // sentence*64 + t
        int e   = (slot & 31) << 3;
        int tok = docs[row];
        cvt8(xb + (size_t)slot * 8, embed + (size_t)tok * EMB + e);
    }
    cvt8(whh + (size_t)gid * 8,             w_hh_f + (size_t)gid * 8);
    cvt8(whh + (size_t)(gid + 131072) * 8,  w_hh_b + (size_t)gid * 8);
    {
        int dir0 = gid >> 16;
        int idx  = gid & 65535;
        cvt8(wih + (size_t)gid * 8, (dir0 ? w_ih_b : w_ih_f) + (size_t)idx * 8);
    }
    {
        s16x8 z = {0,0,0,0,0,0,0,0};
        *(s16x8*)(hb + (size_t)gid * 8) = z;   // parity-0, both dirs
    }
    if (gid < NROW) {
        int c = 0;
        const int* dr = docs + gid * SEQ;
        for (int s2 = 0; s2 < SEQ; ++s2) c += (dr[s2] != 0);
        sl[gid] = c;
    }
    if (gid < 8) bar[gid] = 0u;

    cg::this_grid().sync();

    // ---------------- decode block role (verbatim R1) ----------------
    const int grp = bid & 7;         // barrier group: 32 WGs each (same dir,rg)
    const int dir = grp >> 2;        // 0 fwd, 1 bwd
    const int rg  = grp & 3;         // row group (256 rows)
    const int cgd = bid >> 3;        // 0..31 : hidden-unit chunk of 16
    const int rowbase = rg * 256;
    const int hubase  = cgd * 16;

    // ---------------- W -> LDS, FRAGMENT order (reads use R1's proven gn*HID+k addressing) ----------------
    {
        const unsigned short* whh_d = whh + (size_t)dir * 2048 * HID;
        const unsigned short* wih_d = wih + (size_t)dir * 2048 * EMB;
        for (int s2 = 0; s2 < 12; ++s2) {
            int S = s2 * NTHR + tid;        // 0..6143 oct-slots = [24 kc][4 g][64 lane]
            int f = S >> 6, lane_s = S & 63;
            int kc = f >> 2, g = f & 3;
            int l15s = lane_s & 15, lqs = lane_s >> 4;
            int gn = g * HID + hubase + l15s;
            int k  = kc * 32 + lqs * 8;
            const unsigned short* src = (k < HID)
                ? (whh_d + (size_t)gn * HID + k)
                : (wih_d + (size_t)gn * EMB + (k - HID));
            *(s16x8*)(Wf + (size_t)S * 8) = *(const s16x8*)src;
        }
    }
    __syncthreads();

    // ---------------- per-lane setup (verbatim R1) ----------------
    const int wid = tid >> 6, lane = tid & 63, l15 = lane & 15, lq = lane >> 4;
    const int hu = hubase + l15;
    const float* bsrc = dir ? b_b : b_f;
    const float bi_ = bsrc[hu], bf_ = bsrc[HID + hu], bg_ = bsrc[2 * HID + hu], bo_ = bsrc[3 * HID + hu];

    int rA[2];
    rA[0] = rowbase + wid * 32 + l15;
    rA[1] = rowbase + wid * 32 + 16 + l15;

    int gr8[8]; int sl8[8]; float c8[8], pool8[8];
    #pragma unroll
    for (int rf = 0; rf < 2; ++rf)
        #pragma unroll
        for (int r = 0; r < 4; ++r) {
            int k8 = rf * 4 + r;
            gr8[k8] = rowbase + wid * 32 + rf * 16 + lq * 4 + r;
            sl8[k8] = sl[gr8[k8]];
            c8[k8] = 0.f; pool8[k8] = 0.f;
        }

    // ---------------- recurrence ----------------
    #pragma unroll 1
    for (int t = 0; t < SEQ; ++t) {
        const int te = dir ? (SEQ - 1 - t) : t;
        const unsigned short* hrd = hb + (size_t)((t & 1) * 2 + dir) * NROW * HID;
        unsigned short* hwr       = hb + (size_t)((((t + 1) & 1)) * 2 + dir) * NROW * HID;

        f32x4 acc[2][4];
        #pragma unroll
        for (int rf = 0; rf < 2; ++rf)
            #pragma unroll
            for (int g = 0; g < 4; ++g)
                acc[rf][g] = (f32x4){0.f, 0.f, 0.f, 0.f};

        // A-chunk loads straight from global (h for kc<16, x for kc>=16)
        auto ldA = [&](s16x8* dst, int kc) {
            #pragma unroll
            for (int rf = 0; rf < 2; ++rf) {
                const unsigned short* p = (kc < 16)
                    ? hrd + (size_t)rA[rf] * HID + kc * 32 + lq * 8
                    : xb + ((size_t)rA[rf] * SEQ + te) * EMB + (kc - 16) * 32 + lq * 8;
                dst[rf] = *(const s16x8*)p;
            }
        };

        s16x8 Abuf[2][2];   // [parity][rf]; prefetch distance 1 => write buf != read buf, no WAR hazard
        ldA(Abuf[0], 0);
        #pragma unroll
        for (int kc = 0; kc < 24; ++kc) {
            if (kc < 23) ldA(Abuf[(kc + 1) & 1], kc + 1);
            s16x8 Bf[4];
            #pragma unroll
            for (int g = 0; g < 4; ++g)
                Bf[g] = *(const s16x8*)(Wf + ((size_t)(kc * 4 + g) * 64 + lane) * 8);
            #pragma unroll
            for (int rf = 0; rf < 2; ++rf)
                #pragma unroll
                for (int g = 0; g < 4; ++g)
                    acc[rf][g] = __builtin_amdgcn_mfma_f32_16x16x32_bf16(
                        Abuf[kc & 1][rf], Bf[g], acc[rf][g], 0, 0, 0);
        }

        // elementwise LSTM update (verbatim R1); gates i,f,g,o in same lane
        #pragma unroll
        for (int rf = 0; rf < 2; ++rf) {
            #pragma unroll
            for (int r = 0; r < 4; ++r) {
                int k8 = rf * 4 + r;
                float iv = acc[rf][0][r] + bi_;
                float fv = acc[rf][1][r] + bf_;
                float gv = acc[rf][2][r] + bg_;
                float ov = acc[rf][3][r] + bo_;
                float cc = sigf(fv) * c8[k8] + sigf(iv) * tanh_(gv);
                c8[k8] = cc;
                float hh = sigf(ov) * tanh_(cc);
                hwr[(size_t)gr8[k8] * HID + hu] = f2bf(hh);
                if (te < sl8[k8]) pool8[k8] += hh;
            }
        }

        // 32-WG group barrier (verbatim R1)
        __syncthreads();
        if (tid == 0) {
            __threadfence();
            __hip_atomic_fetch_add(bar + grp, 1u, __ATOMIC_RELAXED, __HIP_MEMORY_SCOPE_AGENT);
            unsigned tgt = 32u * (unsigned)(t + 1);
            while (__hip_atomic_load(bar + grp, __ATOMIC_RELAXED, __HIP_MEMORY_SCOPE_AGENT) < tgt)
                __builtin_amdgcn_s_sleep(1);
            __threadfence();
        }
        __syncthreads();
    }

    // ---------------- pooled output (verbatim R1) ----------------
    #pragma unroll
    for (int k8 = 0; k8 < 8; ++k8) {
        int gr = gr8[k8];
        int b = gr >> 5, d = gr & 31;
        float denom = (float)(sl8[k8] > 0 ? sl8[k8] : 1);
        float v = (d < doc_lens[b]) ? (pool8[k8] / denom) : 0.f;
        out[(size_t)gr * 1024 + (size_t)dir * HID + hu] = v;
    }
}

extern "C" void kernel_launch(void* const* d_in, const int* in_sizes, int n_in,
                              void* d_out, int out_size, void* d_ws, size_t ws_size,
                              hipStream_t stream) {
    const int*   docs     = (const int*)d_in[0];
    const int*   doc_lens = (const int*)d_in[1];
    /* d_in[2] = max_doc_len scalar (unused; fixed 32) */
    const float* embed    = (const float*)d_in[3];
    const float* w_ih_f   = (const float*)d_in[4];
    const float* w_hh_f   = (const float*)d_in[5];
    const float* b_f      = (const float*)d_in[6];
    const float* w_ih_b   = (const float*)d_in[7];
    const float* w_hh_b   = (const float*)d_in[8];
    const float* b_b      = (const float*)d_in[9];
    float* out = (float*)d_out;
    unsigned char* wsp = (unsigned char*)d_ws;

    (void)in_sizes; (void)n_in; (void)out_size; (void)ws_size;

    hipFuncSetAttribute((const void*)lstm_enc,
                        hipFuncAttributeMaxDynamicSharedMemorySize, LDS_BYTES);

    void* args[] = { &docs, &doc_lens, &embed, &w_ih_f, &w_hh_f, &b_f,
                     &w_ih_b, &w_hh_b, &b_b, &out, &wsp };
    hipLaunchCooperativeKernel((void*)lstm_enc, dim3(NGRID), dim3(NTHR),
                               args, (unsigned)LDS_BYTES, stream);
}

// Round 5
// 1340.623 us; speedup vs baseline: 1.5317x; 1.4498x over previous
//
#include <hip/hip_runtime.h>
#include <hip/hip_bf16.h>
#include <hip/hip_cooperative_groups.h>

namespace cg = cooperative_groups;

typedef __attribute__((ext_vector_type(4))) float f32x4;
typedef __attribute__((ext_vector_type(8))) short s16x8;

// problem constants (fixed instance)
#define SEQ   64
#define EMB   256
#define HID   512
#define NROW  1024          // sentences
#define NTHR  512
#define NGRID 256
#define LDS_BYTES 98304     // 24 kc * 4 gates * 64 lanes * 16B, fragment-order W

// workspace layout (bytes) — identical to the R1/R4 (passing) layout
#define XB_OFF   0ull                                   // bf16 x: [65536][256]
#define WHH_OFF  (XB_OFF + 65536ull * EMB * 2)          // bf16 [2][2048][512]
#define WIH_OFF  (WHH_OFF + 2ull * 2048 * HID * 2)      // bf16 [2][2048][256]
#define HB_OFF   (WIH_OFF + 2ull * 2048 * EMB * 2)      // bf16 [2 parity][2 dir][1024][512]
#define SL_OFF   (HB_OFF + 4ull * NROW * HID * 2)       // int [1024]
#define BAR_OFF  (SL_OFF + 4096ull)                     // unsigned [8]

__device__ __forceinline__ unsigned short f2bf(float f) {
    union { float f; unsigned u; } x; x.f = f;
    unsigned r = x.u + 0x7fffu + ((x.u >> 16) & 1u);   // RNE
    return (unsigned short)(r >> 16);
}
__device__ __forceinline__ void cvt8(unsigned short* dst, const float* src) {
    f32x4 v0 = *(const f32x4*)src;
    f32x4 v1 = *(const f32x4*)(src + 4);
    s16x8 o;
    o[0] = (short)f2bf(v0[0]); o[1] = (short)f2bf(v0[1]);
    o[2] = (short)f2bf(v0[2]); o[3] = (short)f2bf(v0[3]);
    o[4] = (short)f2bf(v1[0]); o[5] = (short)f2bf(v1[1]);
    o[6] = (short)f2bf(v1[2]); o[7] = (short)f2bf(v1[3]);
    *(s16x8*)dst = o;
}
__device__ __forceinline__ float sigf(float x)  { return 1.0f / (1.0f + __expf(-x)); }
__device__ __forceinline__ float tanh_(float x) { return 2.0f / (1.0f + __expf(-2.0f * x)) - 1.0f; }

__global__ void __launch_bounds__(NTHR, 2)
lstm_enc(const int* __restrict__ docs, const int* __restrict__ doc_lens,
         const float* __restrict__ embed,
         const float* __restrict__ w_ih_f, const float* __restrict__ w_hh_f, const float* __restrict__ b_f,
         const float* __restrict__ w_ih_b, const float* __restrict__ w_hh_b, const float* __restrict__ b_b,
         float* __restrict__ out, unsigned char* __restrict__ ws)
{
    extern __shared__ unsigned short Wf[];   // [24 kc][4 g][64 lane][8] bf16, MFMA B-frag order

    unsigned short* xb  = (unsigned short*)(ws + XB_OFF);
    unsigned short* whh = (unsigned short*)(ws + WHH_OFF);
    unsigned short* wih = (unsigned short*)(ws + WIH_OFF);
    unsigned short* hb  = (unsigned short*)(ws + HB_OFF);
    int*       sl  = (int*)(ws + SL_OFF);
    unsigned*  bar = (unsigned*)(ws + BAR_OFF);

    const int tid = threadIdx.x;
    const int bid = blockIdx.x;
    const int gid = bid * NTHR + tid;        // 0..131071

    // ---------------- phase 0: convert / gather / init (verbatim R4) ----------------
    for (int i = 0; i < 16; ++i) {
        int slot = gid + i * (NGRID * NTHR);
        int row = slot >> 5;                // sentence*64 + t
        int e   = (slot & 31) << 3;
        int tok = docs[row];
        cvt8(xb + (size_t)slot * 8, embed + (size_t)tok * EMB + e);
    }
    cvt8(whh + (size_t)gid * 8,             w_hh_f + (size_t)gid * 8);
    cvt8(whh + (size_t)(gid + 131072) * 8,  w_hh_b + (size_t)gid * 8);
    {
        int dir0 = gid >> 16;
        int idx  = gid & 65535;
        cvt8(wih + (size_t)gid * 8, (dir0 ? w_ih_b : w_ih_f) + (size_t)idx * 8);
    }
    {
        s16x8 z = {0,0,0,0,0,0,0,0};
        *(s16x8*)(hb + (size_t)gid * 8) = z;   // parity-0, both dirs (flushed by grid.sync fence)
    }
    if (gid < NROW) {
        int c = 0;
        const int* dr = docs + gid * SEQ;
        for (int s2 = 0; s2 < SEQ; ++s2) c += (dr[s2] != 0);
        sl[gid] = c;
    }
    if (gid < 8) bar[gid] = 0u;

    cg::this_grid().sync();

    // ---------------- decode block role (verbatim R4) ----------------
    const int grp = bid & 7;         // barrier group: 32 WGs each (same dir,rg); XCD-local heuristic
    const int dir = grp >> 2;        // 0 fwd, 1 bwd
    const int rg  = grp & 3;         // row group (256 rows)
    const int cgd = bid >> 3;        // 0..31 : hidden-unit chunk of 16
    const int rowbase = rg * 256;
    const int hubase  = cgd * 16;

    // ---------------- W -> LDS, FRAGMENT order (verbatim R4) ----------------
    {
        const unsigned short* whh_d = whh + (size_t)dir * 2048 * HID;
        const unsigned short* wih_d = wih + (size_t)dir * 2048 * EMB;
        for (int s2 = 0; s2 < 12; ++s2) {
            int S = s2 * NTHR + tid;        // 0..6143 oct-slots = [24 kc][4 g][64 lane]
            int f = S >> 6, lane_s = S & 63;
            int kc = f >> 2, g = f & 3;
            int l15s = lane_s & 15, lqs = lane_s >> 4;
            int gn = g * HID + hubase + l15s;
            int k  = kc * 32 + lqs * 8;
            const unsigned short* src = (k < HID)
                ? (whh_d + (size_t)gn * HID + k)
                : (wih_d + (size_t)gn * EMB + (k - HID));
            *(s16x8*)(Wf + (size_t)S * 8) = *(const s16x8*)src;
        }
    }
    __syncthreads();

    // ---------------- per-lane setup (verbatim R4) ----------------
    const int wid = tid >> 6, lane = tid & 63, l15 = lane & 15, lq = lane >> 4;
    const int hu = hubase + l15;
    const float* bsrc = dir ? b_b : b_f;
    const float bi_ = bsrc[hu], bf_ = bsrc[HID + hu], bg_ = bsrc[2 * HID + hu], bo_ = bsrc[3 * HID + hu];

    int rA[2];
    rA[0] = rowbase + wid * 32 + l15;
    rA[1] = rowbase + wid * 32 + 16 + l15;

    int gr8[8]; int sl8[8]; float c8[8], pool8[8];
    #pragma unroll
    for (int rf = 0; rf < 2; ++rf)
        #pragma unroll
        for (int r = 0; r < 4; ++r) {
            int k8 = rf * 4 + r;
            gr8[k8] = rowbase + wid * 32 + rf * 16 + lq * 4 + r;
            sl8[k8] = sl[gr8[k8]];
            c8[k8] = 0.f; pool8[k8] = 0.f;
        }

    // ---------------- recurrence ----------------
    #pragma unroll 1
    for (int t = 0; t < SEQ; ++t) {
        const int te = dir ? (SEQ - 1 - t) : t;
        const unsigned short* hrd = hb + (size_t)((t & 1) * 2 + dir) * NROW * HID;
        unsigned short* hwr       = hb + (size_t)((((t + 1) & 1)) * 2 + dir) * NROW * HID;

        f32x4 acc[2][4];
        #pragma unroll
        for (int rf = 0; rf < 2; ++rf)
            #pragma unroll
            for (int g = 0; g < 4; ++g)
                acc[rf][g] = (f32x4){0.f, 0.f, 0.f, 0.f};

        // A-chunk loads straight from global (h for kc<16, x for kc>=16) — plain cached loads;
        // freshness guaranteed by the buffer_inv emitted by the barrier's acquire load below.
        auto ldA = [&](s16x8* dst, int kc) {
            #pragma unroll
            for (int rf = 0; rf < 2; ++rf) {
                const unsigned short* p = (kc < 16)
                    ? hrd + (size_t)rA[rf] * HID + kc * 32 + lq * 8
                    : xb + ((size_t)rA[rf] * SEQ + te) * EMB + (kc - 16) * 32 + lq * 8;
                dst[rf] = *(const s16x8*)p;
            }
        };

        s16x8 Abuf[2][2];   // [parity][rf]; prefetch distance 1 => write buf != read buf, no WAR hazard
        ldA(Abuf[0], 0);
        #pragma unroll
        for (int kc = 0; kc < 24; ++kc) {
            if (kc < 23) ldA(Abuf[(kc + 1) & 1], kc + 1);
            s16x8 Bf[4];
            #pragma unroll
            for (int g = 0; g < 4; ++g)
                Bf[g] = *(const s16x8*)(Wf + ((size_t)(kc * 4 + g) * 64 + lane) * 8);
            #pragma unroll
            for (int rf = 0; rf < 2; ++rf)
                #pragma unroll
                for (int g = 0; g < 4; ++g)
                    acc[rf][g] = __builtin_amdgcn_mfma_f32_16x16x32_bf16(
                        Abuf[kc & 1][rf], Bf[g], acc[rf][g], 0, 0, 0);
        }

        // elementwise LSTM update; h stores are device-scope write-through atomics
        // (global_store_short sc0 sc1): globally visible once vmcnt retires — no wbl2 needed.
        #pragma unroll
        for (int rf = 0; rf < 2; ++rf) {
            #pragma unroll
            for (int r = 0; r < 4; ++r) {
                int k8 = rf * 4 + r;
                float iv = acc[rf][0][r] + bi_;
                float fv = acc[rf][1][r] + bf_;
                float gv = acc[rf][2][r] + bg_;
                float ov = acc[rf][3][r] + bo_;
                float cc = sigf(fv) * c8[k8] + sigf(iv) * tanh_(gv);
                c8[k8] = cc;
                float hh = sigf(ov) * tanh_(cc);
                __hip_atomic_store(hwr + (size_t)gr8[k8] * HID + hu, f2bf(hh),
                                   __ATOMIC_RELAXED, __HIP_MEMORY_SCOPE_AGENT);
                if (te < sl8[k8]) pool8[k8] += hh;
            }
        }

        // 32-WG group barrier. __syncthreads() emits per-wave s_waitcnt vmcnt(0) before
        // s_barrier -> all waves' write-through h stores are globally visible before the
        // counter increment. Acquire load after the spin emits one buffer_inv sc1
        // (flash invalidate, no writeback walk) so subsequent plain loads see fresh h.
        __syncthreads();
        if (tid == 0) {
            __hip_atomic_fetch_add(bar + grp, 1u, __ATOMIC_RELAXED, __HIP_MEMORY_SCOPE_AGENT);
            unsigned tgt = 32u * (unsigned)(t + 1);
            while (__hip_atomic_load(bar + grp, __ATOMIC_RELAXED, __HIP_MEMORY_SCOPE_AGENT) < tgt)
                __builtin_amdgcn_s_sleep(1);
            (void)__hip_atomic_load(bar + grp, __ATOMIC_ACQUIRE, __HIP_MEMORY_SCOPE_AGENT);
        }
        __syncthreads();
    }

    // ---------------- pooled output (verbatim R4) ----------------
    #pragma unroll
    for (int k8 = 0; k8 < 8; ++k8) {
        int gr = gr8[k8];
        int b = gr >> 5, d = gr & 31;
        float denom = (float)(sl8[k8] > 0 ? sl8[k8] : 1);
        float v = (d < doc_lens[b]) ? (pool8[k8] / denom) : 0.f;
        out[(size_t)gr * 1024 + (size_t)dir * HID + hu] = v;
    }
}

extern "C" void kernel_launch(void* const* d_in, const int* in_sizes, int n_in,
                              void* d_out, int out_size, void* d_ws, size_t ws_size,
                              hipStream_t stream) {
    const int*   docs     = (const int*)d_in[0];
    const int*   doc_lens = (const int*)d_in[1];
    /* d_in[2] = max_doc_len scalar (unused; fixed 32) */
    const float* embed    = (const float*)d_in[3];
    const float* w_ih_f   = (const float*)d_in[4];
    const float* w_hh_f   = (const float*)d_in[5];
    const float* b_f      = (const float*)d_in[6];
    const float* w_ih_b   = (const float*)d_in[7];
    const float* w_hh_b   = (const float*)d_in[8];
    const float* b_b      = (const float*)d_in[9];
    float* out = (float*)d_out;
    unsigned char* wsp = (unsigned char*)d_ws;

    (void)in_sizes; (void)n_in; (void)out_size; (void)ws_size;

    hipFuncSetAttribute((const void*)lstm_enc,
                        hipFuncAttributeMaxDynamicSharedMemorySize, LDS_BYTES);

    void* args[] = { &docs, &doc_lens, &embed, &w_ih_f, &w_hh_f, &b_f,
                     &w_ih_b, &w_hh_b, &b_b, &out, &wsp };
    hipLaunchCooperativeKernel((void*)lstm_enc, dim3(NGRID), dim3(NTHR),
                               args, (unsigned)LDS_BYTES, stream);
}